// Round 3
// baseline (4390.928 us; speedup 1.0000x reference)
//
#include <hip/hip_runtime.h>

#define V_N 20000
#define E_N 100000
#define NODE_IN_F 128
#define EDGE_IN_F 128
#define H 64
#define EDGE_HID 128
#define OUT_F 64
#define STEPS 9

typedef __attribute__((ext_vector_type(8))) short bf16x8;
typedef __attribute__((ext_vector_type(4))) float f32x4;

__device__ __forceinline__ unsigned short f2bf(float f) {
    union { float f; unsigned int u; } v; v.f = f;
    unsigned int u = v.u;
    unsigned int r = (u + 0x7fffu + ((u >> 16) & 1u)) >> 16;  // RNE
    return (unsigned short)r;
}

__device__ __forceinline__ float dot4(float4 w, float4 x) {
    return w.x * x.x + w.y * x.y + w.z * x.z + w.w * x.w;
}

// h0 = relu(nf @ w_p1.T + b_p1) @ w_p2.T + b_p2  (V,64) fp32; also zero agg
__global__ __launch_bounds__(64) void k_project(
    const float* __restrict__ nf,
    const float* __restrict__ w1, const float* __restrict__ b1,
    const float* __restrict__ w2, const float* __restrict__ b2,
    float* __restrict__ h, float* __restrict__ agg)
{
    int v = blockIdx.x, t = threadIdx.x;
    __shared__ float x[NODE_IN_F], tm[H];
    const float* row = nf + (size_t)v * NODE_IN_F;
    x[t] = row[t];
    x[t + 64] = row[t + 64];
    agg[(size_t)v * H + t] = 0.f;
    __syncthreads();
    float acc = b1[t];
    const float4* wr = (const float4*)(w1 + (size_t)t * NODE_IN_F);
    #pragma unroll
    for (int q = 0; q < NODE_IN_F / 4; ++q) acc += dot4(wr[q], *(const float4*)&x[q * 4]);
    tm[t] = fmaxf(acc, 0.f);
    __syncthreads();
    float acc2 = b2[t];
    const float4* wr2 = (const float4*)(w2 + (size_t)t * H);
    #pragma unroll
    for (int q = 0; q < H / 4; ++q) acc2 += dot4(wr2[q], *(const float4*)&tm[q * 4]);
    h[(size_t)v * H + t] = acc2;
}

// g = relu(ef @ w_e1.T + b_e1) -> (E,128) bf16. 32 edges/block, 256 thr.
// thread (eg = tid>>7, c = tid&127) computes 16 edges for column c with the
// w_e1 row chunk held in a register (weight traffic amortized 16x).
__global__ __launch_bounds__(256) void k_edge_g(
    const float* __restrict__ ef,
    const float* __restrict__ w1, const float* __restrict__ b1,
    unsigned short* __restrict__ g)
{
    int tid = threadIdx.x;
    int e0 = blockIdx.x * 32;
    int c = tid & 127, eg = tid >> 7;
    __shared__ float xe[32][132];   // row stride 132 floats: 528 B, 16B-aligned
    for (int idx = tid; idx < 1024; idx += 256) {   // 32 rows x 32 float4
        int e = idx >> 5, kq = idx & 31;
        float4 v = *(const float4*)(ef + (size_t)(e0 + e) * EDGE_IN_F + kq * 4);
        *(float4*)&xe[e][kq * 4] = v;
    }
    __syncthreads();
    float acc[16];
    #pragma unroll
    for (int j = 0; j < 16; ++j) acc[j] = b1[c];
    const float4* wr = (const float4*)(w1 + (size_t)c * EDGE_IN_F);
    for (int kb = 0; kb < EDGE_IN_F / 4; ++kb) {
        float4 w = wr[kb];
        #pragma unroll
        for (int j = 0; j < 16; ++j) {
            float4 x = *(const float4*)&xe[eg * 16 + j][kb * 4];
            acc[j] += dot4(w, x);
        }
    }
    #pragma unroll
    for (int j = 0; j < 16; ++j)
        g[(size_t)(e0 + eg * 16 + j) * EDGE_HID + c] = f2bf(fmaxf(acc[j], 0.f));
}

// w_e2 fp32 -> bf16 (4096x128, 1 MB) once per launch
__global__ __launch_bounds__(256) void k_w2bf(
    const float* __restrict__ w2, unsigned short* __restrict__ w2b)
{
    int idx = blockIdx.x * 256 + threadIdx.x;   // 0..131071, x4 elements
    float4 v = *(const float4*)(w2 + (size_t)idx * 4);
    ushort4 o;
    o.x = f2bf(v.x); o.y = f2bf(v.y); o.z = f2bf(v.z); o.w = f2bf(v.w);
    *(ushort4*)(w2b + (size_t)idx * 4) = o;
}

// hb[v,o] = sum_i h[v,i] * b_e2[i*64+o]. 16 nodes/block, 256 thr.
__global__ __launch_bounds__(256) void k_hb(
    const float* __restrict__ h, const float* __restrict__ b2,
    float* __restrict__ hb)
{
    int tid = threadIdx.x;
    int o = tid & 63, grp = tid >> 6;
    int vbase = blockIdx.x * 16;
    __shared__ float hl[16][68];
    for (int idx = tid; idx < 16 * 64; idx += 256) {
        int n = idx >> 6, i = idx & 63;
        hl[n][i] = h[(size_t)(vbase + n) * H + i];
    }
    __syncthreads();
    float acc[4] = {0.f, 0.f, 0.f, 0.f};
    for (int i = 0; i < H; ++i) {
        float w = b2[i * 64 + o];   // coalesced across lanes
        #pragma unroll
        for (int n = 0; n < 4; ++n) acc[n] += hl[grp * 4 + n][i] * w;
    }
    #pragma unroll
    for (int n = 0; n < 4; ++n)
        hb[(size_t)(vbase + grp * 4 + n) * H + o] = acc[n];
}

// Fused NNConv message + scatter:
//   msg[e,o] = sum_i h[src[e],i] * ( sum_k g[e,k]*w2[(i*64+o),k] ) + hb[src[e],o]
//   agg[dst[e],o] += msg[e,o]
// Block = 256 thr (4 waves) x 32 edges; wave wv covers o in [wv*16, wv*16+16).
// Per i: MFMA 16x16x32 bf16 (A = g frags in regs, B = w2b rows from L2) makes a
// We tile (16e x 16o); rows scaled by h_s[e][i], folded into msg accumulators.
// Layouts: A[m=lane&15][k=q*8+j], B lane n holds row n over k, D col=lane&15 row=q*4+r.
__global__ __launch_bounds__(256) void k_msg_fused(
    const float* __restrict__ h, const unsigned short* __restrict__ g,
    const unsigned short* __restrict__ w2b, const float* __restrict__ hb,
    const int* __restrict__ src, const int* __restrict__ dst,
    float* __restrict__ agg)
{
    int tid = threadIdx.x;
    int wv = tid >> 6, lane = tid & 63;
    int m = lane & 15, q = lane >> 4;
    int e0 = blockIdx.x * 32;
    int o0 = wv * 16;
    __shared__ float h_s[32][65];
    __shared__ int src_s[32], dst_s[32];
    if (tid < 32) { src_s[tid] = src[e0 + tid]; dst_s[tid] = dst[e0 + tid]; }
    __syncthreads();
    for (int idx = tid; idx < 32 * 64; idx += 256) {
        int e = idx >> 6, i = idx & 63;
        h_s[e][i] = h[(size_t)src_s[e] * H + i];
    }
    bf16x8 a0[4], a1[4];
    const unsigned short* ga0 = g + (size_t)(e0 + m) * EDGE_HID + q * 8;
    const unsigned short* ga1 = g + (size_t)(e0 + 16 + m) * EDGE_HID + q * 8;
    #pragma unroll
    for (int kb = 0; kb < 4; ++kb) {
        a0[kb] = *(const bf16x8*)(ga0 + kb * 32);
        a1[kb] = *(const bf16x8*)(ga1 + kb * 32);
    }
    __syncthreads();
    f32x4 msg0 = {0.f, 0.f, 0.f, 0.f}, msg1 = {0.f, 0.f, 0.f, 0.f};
    const unsigned short* pb = w2b + (size_t)(o0 + m) * EDGE_HID + q * 8;
    const float* h0 = &h_s[q * 4][0];
    const float* h1 = &h_s[16 + q * 4][0];
    #pragma unroll 2
    for (int i = 0; i < 64; ++i) {
        f32x4 d0 = {0.f, 0.f, 0.f, 0.f}, d1 = {0.f, 0.f, 0.f, 0.f};
        #pragma unroll
        for (int kb = 0; kb < 4; ++kb) {
            bf16x8 b = *(const bf16x8*)(pb + (size_t)i * 8192 + kb * 32);
            d0 = __builtin_amdgcn_mfma_f32_16x16x32_bf16(a0[kb], b, d0, 0, 0, 0);
            d1 = __builtin_amdgcn_mfma_f32_16x16x32_bf16(a1[kb], b, d1, 0, 0, 0);
        }
        #pragma unroll
        for (int r = 0; r < 4; ++r) {
            msg0[r] += h0[r * 65 + i] * d0[r];
            msg1[r] += h1[r * 65 + i] * d1[r];
        }
    }
    #pragma unroll
    for (int r = 0; r < 4; ++r) {
        int el0 = q * 4 + r, el1 = 16 + q * 4 + r;
        int o = o0 + m;
        float v0 = msg0[r] + hb[(size_t)src_s[el0] * H + o];
        float v1 = msg1[r] + hb[(size_t)src_s[el1] * H + o];
        atomicAdd(&agg[(size_t)dst_s[el0] * H + o], v0);
        atomicAdd(&agg[(size_t)dst_s[el1] * H + o], v1);
    }
}

// GRUCell over 16 nodes/block; x = relu(agg + b_conv); agg re-zeroed for next step.
__global__ __launch_bounds__(256) void k_gru(
    float* __restrict__ agg, const float* __restrict__ b_conv,
    const float* __restrict__ w_ih, const float* __restrict__ w_hh,
    const float* __restrict__ b_ih, const float* __restrict__ b_hh,
    float* __restrict__ h)
{
    int tid = threadIdx.x;
    int o = tid & 63, grp = tid >> 6;
    int vbase = blockIdx.x * 16;
    __shared__ float xl[16][68], hl[16][68];
    for (int idx = tid; idx < 16 * 64; idx += 256) {
        int n = idx >> 6, i = idx & 63;
        size_t p = (size_t)(vbase + n) * H + i;
        float a = agg[p];
        agg[p] = 0.f;
        xl[n][i] = fmaxf(a + b_conv[i], 0.f);
        hl[n][i] = h[p];
    }
    __syncthreads();
    float gir[4], giz[4], gin[4], ghr[4], ghz[4], ghn[4];
    #pragma unroll
    for (int n = 0; n < 4; ++n) {
        gir[n] = b_ih[o];       ghr[n] = b_hh[o];
        giz[n] = b_ih[64 + o];  ghz[n] = b_hh[64 + o];
        gin[n] = b_ih[128 + o]; ghn[n] = b_hh[128 + o];
    }
    const float4* wir = (const float4*)(w_ih + (size_t)o * H);
    const float4* wiz = (const float4*)(w_ih + (size_t)(64 + o) * H);
    const float4* win = (const float4*)(w_ih + (size_t)(128 + o) * H);
    const float4* whr = (const float4*)(w_hh + (size_t)o * H);
    const float4* whz = (const float4*)(w_hh + (size_t)(64 + o) * H);
    const float4* whn = (const float4*)(w_hh + (size_t)(128 + o) * H);
    #pragma unroll 4
    for (int qq = 0; qq < H / 4; ++qq) {
        float4 a1 = wir[qq], a2 = wiz[qq], a3 = win[qq];
        float4 c1 = whr[qq], c2 = whz[qq], c3 = whn[qq];
        #pragma unroll
        for (int n = 0; n < 4; ++n) {
            float4 xv = *(const float4*)&xl[grp * 4 + n][qq * 4];
            float4 hv = *(const float4*)&hl[grp * 4 + n][qq * 4];
            gir[n] += dot4(a1, xv); giz[n] += dot4(a2, xv); gin[n] += dot4(a3, xv);
            ghr[n] += dot4(c1, hv); ghz[n] += dot4(c2, hv); ghn[n] += dot4(c3, hv);
        }
    }
    #pragma unroll
    for (int n = 0; n < 4; ++n) {
        float hv = hl[grp * 4 + n][o];
        float r = 1.f / (1.f + __expf(-(gir[n] + ghr[n])));
        float z = 1.f / (1.f + __expf(-(giz[n] + ghz[n])));
        float na = gin[n] + r * ghn[n];
        float tn = 1.f - 2.f / (__expf(2.f * na) + 1.f);   // tanh
        h[(size_t)(vbase + grp * 4 + n) * H + o] = (1.f - z) * tn + z * hv;
    }
}

// out = relu(h @ w_d1.T + b_d1) @ w_d2.T + b_d2  -> fp32
__global__ __launch_bounds__(64) void k_decoder(
    const float* __restrict__ h,
    const float* __restrict__ w1, const float* __restrict__ b1,
    const float* __restrict__ w2, const float* __restrict__ b2,
    float* __restrict__ out)
{
    int v = blockIdx.x, t = threadIdx.x;
    __shared__ float hl[H], tl[H];
    hl[t] = h[(size_t)v * H + t];
    __syncthreads();
    float acc = b1[t];
    const float4* wr = (const float4*)(w1 + (size_t)t * H);
    #pragma unroll
    for (int q = 0; q < H / 4; ++q) acc += dot4(wr[q], *(const float4*)&hl[q * 4]);
    tl[t] = fmaxf(acc, 0.f);
    __syncthreads();
    float acc2 = b2[t];
    const float4* wr2 = (const float4*)(w2 + (size_t)t * H);
    #pragma unroll
    for (int q = 0; q < H / 4; ++q) acc2 += dot4(wr2[q], *(const float4*)&tl[q * 4]);
    out[(size_t)v * OUT_F + t] = acc2;
}

extern "C" void kernel_launch(void* const* d_in, const int* in_sizes, int n_in,
                              void* d_out, int out_size, void* d_ws, size_t ws_size,
                              hipStream_t stream) {
    const float* nf     = (const float*)d_in[0];
    const float* ef     = (const float*)d_in[1];
    const int* src      = (const int*)d_in[2];
    const int* dst      = (const int*)d_in[3];
    const float* w_p1   = (const float*)d_in[4];
    const float* b_p1   = (const float*)d_in[5];
    const float* w_p2   = (const float*)d_in[6];
    const float* b_p2   = (const float*)d_in[7];
    const float* w_e1   = (const float*)d_in[8];
    const float* b_e1   = (const float*)d_in[9];
    const float* w_e2   = (const float*)d_in[10];
    const float* b_e2   = (const float*)d_in[11];
    const float* b_conv = (const float*)d_in[12];
    const float* w_ih   = (const float*)d_in[13];
    const float* w_hh   = (const float*)d_in[14];
    const float* b_ih   = (const float*)d_in[15];
    const float* b_hh   = (const float*)d_in[16];
    const float* w_d1   = (const float*)d_in[17];
    const float* b_d1   = (const float*)d_in[18];
    const float* w_d2   = (const float*)d_in[19];
    const float* b_d2   = (const float*)d_in[20];
    (void)b_conv;

    // workspace layout (total 42,008,576 B):
    //   g    : E*128 bf16 = 25,600,000
    //   w2b  : 4096*128 bf16 = 1,048,576
    //   h    : V*64 f32 = 5,120,000
    //   agg  : V*64 f32 = 5,120,000
    //   hb   : V*64 f32 = 5,120,000
    char* ws = (char*)d_ws;
    unsigned short* g   = (unsigned short*)(ws);
    unsigned short* w2b = (unsigned short*)(ws + 25600000LL);
    float* h            = (float*)(ws + 26648576LL);
    float* agg          = (float*)(ws + 31768576LL);
    float* hb           = (float*)(ws + 36888576LL);

    k_project<<<V_N, 64, 0, stream>>>(nf, w_p1, b_p1, w_p2, b_p2, h, agg);
    k_edge_g<<<E_N / 32, 256, 0, stream>>>(ef, w_e1, b_e1, g);
    k_w2bf<<<512, 256, 0, stream>>>(w_e2, w2b);
    for (int s = 0; s < STEPS; ++s) {
        k_hb<<<V_N / 16, 256, 0, stream>>>(h, b_e2, hb);
        k_msg_fused<<<E_N / 32, 256, 0, stream>>>(h, g, w2b, hb, src, dst, agg);
        k_gru<<<V_N / 16, 256, 0, stream>>>(agg, b_conv, w_ih, w_hh, b_ih, b_hh, h);
    }
    k_decoder<<<V_N, 64, 0, stream>>>(h, w_d1, b_d1, w_d2, b_d2, (float*)d_out);
}

// Round 5
// 3061.571 us; speedup vs baseline: 1.4342x; 1.4342x over previous
//
#include <hip/hip_runtime.h>

#define V_N 20000
#define E_N 100000
#define NODE_IN_F 128
#define EDGE_IN_F 128
#define H 64
#define EDGE_HID 128
#define OUT_F 64
#define STEPS 9

typedef __attribute__((ext_vector_type(8))) short bf16x8;
typedef __attribute__((ext_vector_type(4))) float f32x4;

__device__ __forceinline__ unsigned short f2bf(float f) {
    union { float f; unsigned int u; } v; v.f = f;
    unsigned int u = v.u;
    unsigned int r = (u + 0x7fffu + ((u >> 16) & 1u)) >> 16;  // RNE
    return (unsigned short)r;
}

__device__ __forceinline__ float dot4(float4 w, float4 x) {
    return w.x * x.x + w.y * x.y + w.z * x.z + w.w * x.w;
}

// h0 = relu(nf@w1.T+b1)@w2.T+b2 (V,64) fp32; zero agg; hb = h0-row @ b_e2-matrix
__global__ __launch_bounds__(64) void k_project(
    const float* __restrict__ nf,
    const float* __restrict__ w1, const float* __restrict__ b1,
    const float* __restrict__ w2, const float* __restrict__ b2,
    const float* __restrict__ b2e,
    float* __restrict__ h, float* __restrict__ agg, float* __restrict__ hb)
{
    int v = blockIdx.x, t = threadIdx.x;
    __shared__ float x[NODE_IN_F], tm[H];
    const float* row = nf + (size_t)v * NODE_IN_F;
    x[t] = row[t];
    x[t + 64] = row[t + 64];
    agg[(size_t)v * H + t] = 0.f;
    __syncthreads();
    float acc = b1[t];
    const float4* wr = (const float4*)(w1 + (size_t)t * NODE_IN_F);
    #pragma unroll
    for (int q = 0; q < NODE_IN_F / 4; ++q) acc += dot4(wr[q], *(const float4*)&x[q * 4]);
    tm[t] = fmaxf(acc, 0.f);
    __syncthreads();
    float acc2 = b2[t];
    const float4* wr2 = (const float4*)(w2 + (size_t)t * H);
    #pragma unroll
    for (int q = 0; q < H / 4; ++q) acc2 += dot4(wr2[q], *(const float4*)&tm[q * 4]);
    h[(size_t)v * H + t] = acc2;
    __syncthreads();
    x[t] = acc2;           // reuse x as h-row
    __syncthreads();
    float acc3 = 0.f;
    for (int i = 0; i < H; ++i) acc3 += x[i] * b2e[i * 64 + t];
    hb[(size_t)v * H + t] = acc3;
}

// g = relu(ef @ w_e1.T + b_e1) -> (E,128) bf16. 32 edges/block.
__global__ __launch_bounds__(256) void k_edge_g(
    const float* __restrict__ ef,
    const float* __restrict__ w1, const float* __restrict__ b1,
    unsigned short* __restrict__ g)
{
    int tid = threadIdx.x;
    int e0 = blockIdx.x * 32;
    int c = tid & 127, eg = tid >> 7;
    __shared__ float xe[32][132];
    for (int idx = tid; idx < 1024; idx += 256) {
        int e = idx >> 5, kq = idx & 31;
        float4 v = *(const float4*)(ef + (size_t)(e0 + e) * EDGE_IN_F + kq * 4);
        *(float4*)&xe[e][kq * 4] = v;
    }
    __syncthreads();
    float acc[16];
    #pragma unroll
    for (int j = 0; j < 16; ++j) acc[j] = b1[c];
    const float4* wr = (const float4*)(w1 + (size_t)c * EDGE_IN_F);
    for (int kb = 0; kb < EDGE_IN_F / 4; ++kb) {
        float4 w = wr[kb];
        #pragma unroll
        for (int j = 0; j < 16; ++j) {
            float4 x = *(const float4*)&xe[eg * 16 + j][kb * 4];
            acc[j] += dot4(w, x);
        }
    }
    #pragma unroll
    for (int j = 0; j < 16; ++j)
        g[(size_t)(e0 + eg * 16 + j) * EDGE_HID + c] = f2bf(fmaxf(acc[j], 0.f));
}

// w_e2 fp32 -> bf16 (4096x128, 1 MB)
__global__ __launch_bounds__(256) void k_w2bf(
    const float* __restrict__ w2, unsigned short* __restrict__ w2b)
{
    int idx = blockIdx.x * 256 + threadIdx.x;
    float4 v = *(const float4*)(w2 + (size_t)idx * 4);
    ushort4 o;
    o.x = f2bf(v.x); o.y = f2bf(v.y); o.z = f2bf(v.z); o.w = f2bf(v.w);
    *(ushort4*)(w2b + (size_t)idx * 4) = o;
}

// Fused NNConv message + scatter. 64 edges/block (4 groups of 16), 4 waves:
// wave wv covers o in [wv*16, wv*16+16) for ALL 64 edges.
// Per i (input channel): D_i[e,o] = sum_k g[e,k]*w2b[i*64+o][k] via 4 chained
// 16x16x32 MFMAs; msg[e,o] += h[src[e],i] * D_i[e,o]  (scale in fp32, no cvt).
// B fragments software-pipelined depth-4 (branchless, wrap-indexed) so L2
// latency (~200cyc) is covered by ~3 compute bodies.
// Layouts (verified): A[m=lane&15][k=q*8+j], B lane n = row n over k,
// D col=lane&15 (o), row=q*4+r (e within 16-group).
__global__ __launch_bounds__(256) void k_msg_fused(
    const float* __restrict__ h, const unsigned short* __restrict__ g,
    const unsigned short* __restrict__ w2b, const float* __restrict__ hb,
    const int* __restrict__ src, const int* __restrict__ dst,
    float* __restrict__ agg)
{
    int tid = threadIdx.x;
    int wv = tid >> 6, lane = tid & 63;
    int m = lane & 15, q = lane >> 4;
    int e0 = blockIdx.x * 64;
    int o0 = wv * 16;
    __shared__ float h_t[64][68];      // h_t[i][e]; stride 68 floats (16B-aligned rows)
    __shared__ int src_s[64], dst_s[64];
    if (tid < 64) {
        int ee = e0 + tid; if (ee > E_N - 1) ee = E_N - 1;
        src_s[tid] = src[ee]; dst_s[tid] = dst[ee];
    }
    __syncthreads();
    for (int idx = tid; idx < 64 * 64; idx += 256) {
        int e = idx >> 6, i = idx & 63;
        h_t[i][e] = h[(size_t)src_s[e] * H + i];
    }
    // A fragments: 4 edge-groups x 4 k-blocks, bf16 in regs
    bf16x8 a[4][4];
    #pragma unroll
    for (int eg = 0; eg < 4; ++eg) {
        int er = e0 + eg * 16 + m; if (er > E_N - 1) er = E_N - 1;
        const unsigned short* ga = g + (size_t)er * EDGE_HID + q * 8;
        #pragma unroll
        for (int kb = 0; kb < 4; ++kb) a[eg][kb] = *(const bf16x8*)(ga + kb * 32);
    }
    __syncthreads();
    f32x4 msg[4] = {{0.f,0.f,0.f,0.f},{0.f,0.f,0.f,0.f},{0.f,0.f,0.f,0.f},{0.f,0.f,0.f,0.f}};
    const unsigned short* pb = w2b + (size_t)(o0 + m) * EDGE_HID + q * 8;

#define LOADB(B, I) { \
    const unsigned short* pn = pb + (size_t)((I) & 63) * 8192; \
    _Pragma("unroll") \
    for (int kb = 0; kb < 4; ++kb) B[kb] = *(const bf16x8*)(pn + kb * 32); }

#define COMPUTE(I, B) { \
    _Pragma("unroll") \
    for (int eg = 0; eg < 4; ++eg) { \
        f32x4 d = {0.f, 0.f, 0.f, 0.f}; \
        d = __builtin_amdgcn_mfma_f32_16x16x32_bf16(a[eg][0], B[0], d, 0, 0, 0); \
        d = __builtin_amdgcn_mfma_f32_16x16x32_bf16(a[eg][1], B[1], d, 0, 0, 0); \
        d = __builtin_amdgcn_mfma_f32_16x16x32_bf16(a[eg][2], B[2], d, 0, 0, 0); \
        d = __builtin_amdgcn_mfma_f32_16x16x32_bf16(a[eg][3], B[3], d, 0, 0, 0); \
        float4 hv = *(const float4*)&h_t[(I)][eg * 16 + q * 4]; \
        msg[eg][0] += hv.x * d[0]; \
        msg[eg][1] += hv.y * d[1]; \
        msg[eg][2] += hv.z * d[2]; \
        msg[eg][3] += hv.w * d[3]; } }

    bf16x8 bA[4], bB[4], bC[4], bD[4];
    LOADB(bA, 0) LOADB(bB, 1) LOADB(bC, 2) LOADB(bD, 3)
    for (int ii = 0; ii < 64; ii += 4) {
        COMPUTE(ii + 0, bA) LOADB(bA, ii + 4)
        COMPUTE(ii + 1, bB) LOADB(bB, ii + 5)
        COMPUTE(ii + 2, bC) LOADB(bC, ii + 6)
        COMPUTE(ii + 3, bD) LOADB(bD, ii + 7)
    }
#undef LOADB
#undef COMPUTE

    int o = o0 + m;
    #pragma unroll
    for (int eg = 0; eg < 4; ++eg) {
        #pragma unroll
        for (int r = 0; r < 4; ++r) {
            int el = eg * 16 + q * 4 + r;
            if (e0 + el < E_N) {
                float v = msg[eg][r] + hb[(size_t)src_s[el] * H + o];
                atomicAdd(&agg[(size_t)dst_s[el] * H + o], v);
            }
        }
    }
}

// GRU over 16 nodes/block; x=relu(agg+b_conv); agg re-zeroed; epilogue: hb = newh @ b_e2
__global__ __launch_bounds__(256) void k_gru(
    float* __restrict__ agg, const float* __restrict__ b_conv,
    const float* __restrict__ w_ih, const float* __restrict__ w_hh,
    const float* __restrict__ b_ih, const float* __restrict__ b_hh,
    const float* __restrict__ b2e,
    float* __restrict__ h, float* __restrict__ hb)
{
    int tid = threadIdx.x;
    int o = tid & 63, grp = tid >> 6;
    int vbase = blockIdx.x * 16;
    __shared__ float xl[16][68], hl[16][68];
    for (int idx = tid; idx < 16 * 64; idx += 256) {
        int n = idx >> 6, i = idx & 63;
        size_t p = (size_t)(vbase + n) * H + i;
        float a = agg[p];
        agg[p] = 0.f;
        xl[n][i] = fmaxf(a + b_conv[i], 0.f);
        hl[n][i] = h[p];
    }
    __syncthreads();
    float gir[4], giz[4], gin[4], ghr[4], ghz[4], ghn[4];
    #pragma unroll
    for (int n = 0; n < 4; ++n) {
        gir[n] = b_ih[o];       ghr[n] = b_hh[o];
        giz[n] = b_ih[64 + o];  ghz[n] = b_hh[64 + o];
        gin[n] = b_ih[128 + o]; ghn[n] = b_hh[128 + o];
    }
    const float4* wir = (const float4*)(w_ih + (size_t)o * H);
    const float4* wiz = (const float4*)(w_ih + (size_t)(64 + o) * H);
    const float4* win = (const float4*)(w_ih + (size_t)(128 + o) * H);
    const float4* whr = (const float4*)(w_hh + (size_t)o * H);
    const float4* whz = (const float4*)(w_hh + (size_t)(64 + o) * H);
    const float4* whn = (const float4*)(w_hh + (size_t)(128 + o) * H);
    #pragma unroll 4
    for (int qq = 0; qq < H / 4; ++qq) {
        float4 a1 = wir[qq], a2 = wiz[qq], a3 = win[qq];
        float4 c1 = whr[qq], c2 = whz[qq], c3 = whn[qq];
        #pragma unroll
        for (int n = 0; n < 4; ++n) {
            float4 xv = *(const float4*)&xl[grp * 4 + n][qq * 4];
            float4 hv = *(const float4*)&hl[grp * 4 + n][qq * 4];
            gir[n] += dot4(a1, xv); giz[n] += dot4(a2, xv); gin[n] += dot4(a3, xv);
            ghr[n] += dot4(c1, hv); ghz[n] += dot4(c2, hv); ghn[n] += dot4(c3, hv);
        }
    }
    float newh[4];
    #pragma unroll
    for (int n = 0; n < 4; ++n) {
        float hv = hl[grp * 4 + n][o];
        float r = 1.f / (1.f + __expf(-(gir[n] + ghr[n])));
        float z = 1.f / (1.f + __expf(-(giz[n] + ghz[n])));
        float na = gin[n] + r * ghn[n];
        float tn = 1.f - 2.f / (__expf(2.f * na) + 1.f);   // tanh
        newh[n] = (1.f - z) * tn + z * hv;
        h[(size_t)(vbase + grp * 4 + n) * H + o] = newh[n];
    }
    __syncthreads();                 // xl dead; reuse for new h
    #pragma unroll
    for (int n = 0; n < 4; ++n) xl[grp * 4 + n][o] = newh[n];
    __syncthreads();
    float hbacc[4] = {0.f, 0.f, 0.f, 0.f};
    for (int i = 0; i < H; ++i) {
        float w = b2e[i * 64 + o];
        #pragma unroll
        for (int n = 0; n < 4; ++n) hbacc[n] += xl[grp * 4 + n][i] * w;
    }
    #pragma unroll
    for (int n = 0; n < 4; ++n)
        hb[(size_t)(vbase + grp * 4 + n) * H + o] = hbacc[n];
}

// out = relu(h @ w_d1.T + b_d1) @ w_d2.T + b_d2  -> fp32
__global__ __launch_bounds__(64) void k_decoder(
    const float* __restrict__ h,
    const float* __restrict__ w1, const float* __restrict__ b1,
    const float* __restrict__ w2, const float* __restrict__ b2,
    float* __restrict__ out)
{
    int v = blockIdx.x, t = threadIdx.x;
    __shared__ float hl[H], tl[H];
    hl[t] = h[(size_t)v * H + t];
    __syncthreads();
    float acc = b1[t];
    const float4* wr = (const float4*)(w1 + (size_t)t * H);
    #pragma unroll
    for (int q = 0; q < H / 4; ++q) acc += dot4(wr[q], *(const float4*)&hl[q * 4]);
    tl[t] = fmaxf(acc, 0.f);
    __syncthreads();
    float acc2 = b2[t];
    const float4* wr2 = (const float4*)(w2 + (size_t)t * H);
    #pragma unroll
    for (int q = 0; q < H / 4; ++q) acc2 += dot4(wr2[q], *(const float4*)&tl[q * 4]);
    out[(size_t)v * OUT_F + t] = acc2;
}

extern "C" void kernel_launch(void* const* d_in, const int* in_sizes, int n_in,
                              void* d_out, int out_size, void* d_ws, size_t ws_size,
                              hipStream_t stream) {
    const float* nf     = (const float*)d_in[0];
    const float* ef     = (const float*)d_in[1];
    const int* src      = (const int*)d_in[2];
    const int* dst      = (const int*)d_in[3];
    const float* w_p1   = (const float*)d_in[4];
    const float* b_p1   = (const float*)d_in[5];
    const float* w_p2   = (const float*)d_in[6];
    const float* b_p2   = (const float*)d_in[7];
    const float* w_e1   = (const float*)d_in[8];
    const float* b_e1   = (const float*)d_in[9];
    const float* w_e2   = (const float*)d_in[10];
    const float* b_e2   = (const float*)d_in[11];
    const float* b_conv = (const float*)d_in[12];
    const float* w_ih   = (const float*)d_in[13];
    const float* w_hh   = (const float*)d_in[14];
    const float* b_ih   = (const float*)d_in[15];
    const float* b_hh   = (const float*)d_in[16];
    const float* w_d1   = (const float*)d_in[17];
    const float* b_d1   = (const float*)d_in[18];
    const float* w_d2   = (const float*)d_in[19];
    const float* b_d2   = (const float*)d_in[20];

    // workspace layout (total 42,008,576 B):
    //   g    : E*128 bf16 = 25,600,000
    //   w2b  : 4096*128 bf16 = 1,048,576
    //   h    : V*64 f32 = 5,120,000
    //   agg  : V*64 f32 = 5,120,000
    //   hb   : V*64 f32 = 5,120,000
    char* ws = (char*)d_ws;
    unsigned short* g   = (unsigned short*)(ws);
    unsigned short* w2b = (unsigned short*)(ws + 25600000LL);
    float* h            = (float*)(ws + 26648576LL);
    float* agg          = (float*)(ws + 31768576LL);
    float* hb           = (float*)(ws + 36888576LL);

    k_project<<<V_N, 64, 0, stream>>>(nf, w_p1, b_p1, w_p2, b_p2, b_e2, h, agg, hb);
    k_edge_g<<<E_N / 32, 256, 0, stream>>>(ef, w_e1, b_e1, g);
    k_w2bf<<<512, 256, 0, stream>>>(w_e2, w2b);
    for (int s = 0; s < STEPS; ++s) {
        k_msg_fused<<<(E_N + 63) / 64, 256, 0, stream>>>(h, g, w2b, hb, src, dst, agg);
        k_gru<<<V_N / 16, 256, 0, stream>>>(agg, b_conv, w_ih, w_hh, b_ih, b_hh, b_e2, h, hb);
    }
    k_decoder<<<V_N, 64, 0, stream>>>(h, w_d1, b_d1, w_d2, b_d2, (float*)d_out);
}